// Round 4
// baseline (419.564 us; speedup 1.0000x reference)
//
#include <hip/hip_runtime.h>

#define MDIM 8192
#define NDIM 1024
#define FIN  1024
#define DP1  11
#define KDIM 11264            // FIN * 11  (t, T2..T10, x) -- T0 folded into bias
#define KHALF 5632            // split-K half (k elements)
#define ROWB 22528            // bytes per K-row of A / Bt (KDIM * 2)
#define HOFS 2883584u         // 128 rows * ROWB
#define FGOFS 1441792u        // 64 rows * ROWB
#define NT 88                 // K-tiles (of 64) per half
#define NITER 44              // NT / 2

typedef __attribute__((ext_vector_type(8))) short short8;
typedef __attribute__((ext_vector_type(4))) float float4v;
typedef const __attribute__((address_space(1))) unsigned int* gptr_t;
typedef __attribute__((address_space(3))) unsigned int* lptr_t;

// pack two fp32 -> bf16x2 (RNE): low16 = bf16(a), high16 = bf16(b)
__device__ __forceinline__ unsigned int pk2(float a, float b) {
  unsigned int ua = __float_as_uint(a), ub = __float_as_uint(b);
  ua += 0x7FFFu + ((ua >> 16) & 1u);
  ub += 0x7FFFu + ((ub >> 16) & 1u);
  return __builtin_amdgcn_perm(ub, ua, 0x07060302);
}

__device__ __forceinline__ float fast_tanh(float x) {
  float e = __expf(2.f * x);
  return 1.f - 2.f / (e + 1.f);
}

struct Cheb { float t, T2, T3, T4, T5, T6, T7, T8, T9, T10; };
__device__ __forceinline__ Cheb cheb_eval(float x) {
  Cheb c;
  c.t = fast_tanh(x);
  const float t2 = 2.f * c.t;
  c.T2 = t2 * c.t - 1.f;
  c.T3 = t2 * c.T2 - c.t;
  c.T4 = t2 * c.T3 - c.T2;
  c.T5 = t2 * c.T4 - c.T3;
  c.T6 = t2 * c.T5 - c.T4;
  c.T7 = t2 * c.T6 - c.T5;
  c.T8 = t2 * c.T7 - c.T6;
  c.T9 = t2 * c.T8 - c.T7;
  c.T10 = t2 * c.T9 - c.T8;
  return c;
}

// 2 features (22 bf16 = 11 words), feature slots: [t, T2..T10, x]
__device__ __forceinline__ void pack_pair(float xa, float xb, unsigned int* w) {
  Cheb a = cheb_eval(xa), b = cheb_eval(xb);
  w[0] = pk2(a.t, a.T2);  w[1] = pk2(a.T3, a.T4); w[2] = pk2(a.T5, a.T6);
  w[3] = pk2(a.T7, a.T8); w[4] = pk2(a.T9, a.T10); w[5] = pk2(xa, b.t);
  w[6] = pk2(b.T2, b.T3); w[7] = pk2(b.T4, b.T5);  w[8] = pk2(b.T6, b.T7);
  w[9] = pk2(b.T8, b.T9); w[10] = pk2(b.T10, xb);
}

// ---- prep_A: x[8192][1024] -> A bf16 [8192][11264]; LDS-staged coalesced stores
__global__ __launch_bounds__(256) void prep_A_kernel(const float* __restrict__ x,
                                                     unsigned int* __restrict__ A) {
  __shared__ unsigned int rowbuf[5632];   // 22528 B
  const int row = blockIdx.x;
  const int tid = threadIdx.x;
  float4 xv = ((const float4*)(x + (size_t)row * FIN))[tid];
  unsigned int w[22];
  pack_pair(xv.x, xv.y, w);
  pack_pair(xv.z, xv.w, w + 11);
#pragma unroll
  for (int j = 0; j < 22; j++) rowbuf[tid * 22 + j] = w[j];
  __syncthreads();
  uint2* dst = (uint2*)((char*)A + (size_t)row * ROWB);
  const uint2* src = (const uint2*)rowbuf;
#pragma unroll
  for (int j = 0; j < 11; j++) dst[tid + j * 256] = src[tid + j * 256];
}

// ---- prep_B: 1024 blocks: g = feature-group of 8 (0..127), po = o-panel of 128.
// Bt[o][g*176 .. +176): per feature [c1..c10, w] bf16. c0 -> bias[o] (atomic).
// KL: one atomicAdd per block into kl_out (pre-zeroed).
__global__ __launch_bounds__(256) void prep_B_kernel(const float4* __restrict__ mean4,
    const float4* __restrict__ lv4, const float* __restrict__ W,
    const float4* __restrict__ eps4, unsigned short* __restrict__ Bt,
    float* __restrict__ kl_out, float* __restrict__ bias) {
  __shared__ float cf[2816];              // 2 features x 128 o x 11 coeffs
  __shared__ unsigned int pkb[5632];      // 128 o x 44 words = 22528 B
  __shared__ float wsum[4];
  const int tid = threadIdx.x;
  const int g = blockIdx.x >> 3;
  const int po = blockIdx.x & 7;
  float klp = 0.f;
  float biasAcc = 0.f;
#pragma unroll 1
  for (int pr = 0; pr < 4; ++pr) {
#pragma unroll
    for (int f = 0; f < 2; ++f) {
      const int i = g * 8 + pr * 2 + f;
      const size_t b4 = (size_t)i * 2816 + po * 352;   // float4 base of [i][po*128..][*]
#pragma unroll
      for (int qq = 0; qq < 2; ++qq) {
        const int idx = qq * 256 + tid;
        if (idx < 352) {
          float4 m = mean4[b4 + idx];
          float4 l = lv4[b4 + idx];
          float4 e = eps4[b4 + idx];
          float s0 = __expf(0.5f * l.x), s1 = __expf(0.5f * l.y);
          float s2 = __expf(0.5f * l.z), s3 = __expf(0.5f * l.w);
          float4 c;
          c.x = fmaf(e.x, s0, m.x); c.y = fmaf(e.y, s1, m.y);
          c.z = fmaf(e.z, s2, m.z); c.w = fmaf(e.w, s3, m.w);
          klp += (s0 * s0 + m.x * m.x - 1.f - l.x) + (s1 * s1 + m.y * m.y - 1.f - l.y)
               + (s2 * s2 + m.z * m.z - 1.f - l.z) + (s3 * s3 + m.w * m.w - 1.f - l.w);
          ((float4*)cf)[f * 352 + idx] = c;
        }
      }
    }
    __syncthreads();                      // cf complete
    if (tid < 128) {
      const int o = tid;
      const float* ca = &cf[o * DP1];
      const float* cb = &cf[1408 + o * DP1];
      const float wa = W[(size_t)(g * 8 + pr * 2) * NDIM + po * 128 + o];
      const float wb = W[(size_t)(g * 8 + pr * 2 + 1) * NDIM + po * 128 + o];
      biasAcc += ca[0] + cb[0];
      unsigned int* dq = &pkb[o * 44 + pr * 11];
      dq[0] = pk2(ca[1], ca[2]); dq[1] = pk2(ca[3], ca[4]); dq[2] = pk2(ca[5], ca[6]);
      dq[3] = pk2(ca[7], ca[8]); dq[4] = pk2(ca[9], ca[10]); dq[5] = pk2(wa, cb[1]);
      dq[6] = pk2(cb[2], cb[3]); dq[7] = pk2(cb[4], cb[5]); dq[8] = pk2(cb[6], cb[7]);
      dq[9] = pk2(cb[8], cb[9]); dq[10] = pk2(cb[10], wb);
    }
    __syncthreads();                      // pkb slice done; cf reusable
  }
  // write 128 o-rows x 176 B (11 uint4 each)
#pragma unroll
  for (int it = 0; it < 6; ++it) {
    const int cc = it * 256 + tid;
    if (cc < 1408) {
      const int o = cc / 11, c = cc - o * 11;
      uint4 v = *(const uint4*)&pkb[o * 44 + c * 4];
      *(uint4*)((char*)Bt + (size_t)(po * 128 + o) * ROWB + g * 176 + c * 16) = v;
    }
  }
  if (tid < 128) atomicAdd(&bias[po * 128 + tid], biasAcc);
#pragma unroll
  for (int off = 32; off > 0; off >>= 1) klp += __shfl_down(klp, off, 64);
  if ((tid & 63) == 0) wsum[tid >> 6] = klp;
  __syncthreads();
  if (tid == 0) atomicAdd(kl_out, 0.5f * (wsum[0] + wsum[1] + wsum[2] + wsum[3]));
}

// ---- GEMM: 256x256 tile, BK=64, 8 waves (2M x 4N, 128x64 each), split-K x2.
// One barrier per phase + REGISTER-PREFETCHED fragments: body = [STG; (VMW);
// bar; ds-prefetch NEXT phase frags into alt reg set; MFMA on CURRENT regs].
// MFMAs never wait on same-body LDS reads. Staging/VMW ledger identical to r3.
#define VMW(N) asm volatile("s_waitcnt vmcnt(" #N ")" ::: "memory")

// A f-group fg: LDS rows {fg*64..+63} u {128+fg*64..+63} (f-slices 2fg,2fg+1 of both wr)
#define STG_A(p, fg, t) do {                                                              \
    __builtin_amdgcn_global_load_lds((gptr_t)(gA + baseAlo + (fg) * FGOFS + (unsigned)(t) * 128u), \
        (lptr_t)(ldsp + (p) * 65536 + (fg) * 8192 + dA), 16, 0, 0);                       \
    __builtin_amdgcn_global_load_lds((gptr_t)(gA + baseAhi + (fg) * FGOFS + (unsigned)(t) * 128u), \
        (lptr_t)(ldsp + (p) * 65536 + 16384 + (fg) * 8192 + dA), 16, 0, 0);               \
  } while (0)

#define STG_B(p, h, t) do {                                                               \
    __builtin_amdgcn_global_load_lds((gptr_t)(gB + baseB0 + (h) * HOFS + (unsigned)(t) * 128u), \
        (lptr_t)(ldsp + (p) * 65536 + 32768 + (h) * 16384 + dA), 16, 0, 0);               \
    __builtin_amdgcn_global_load_lds((gptr_t)(gB + baseB1 + (h) * HOFS + (unsigned)(t) * 128u), \
        (lptr_t)(ldsp + (p) * 65536 + 32768 + (h) * 16384 + 8192 + dA), 16, 0, 0);        \
  } while (0)

// prefetch A frags for phase (pn, fn) into reg set R[4]
#define PRF_A(pn, fn, R) do {                                                             \
    const char* apn_ = ldsp + (pn) * 65536 + aBase + (fn) * 4096;                         \
    R[0] = *(const short8*)(apn_ + offk0);                                                \
    R[1] = *(const short8*)(apn_ + offk1);                                                \
    R[2] = *(const short8*)(apn_ + 2048 + offk0);                                         \
    R[3] = *(const short8*)(apn_ + 2048 + offk1);                                         \
  } while (0)

// prefetch all B frags of buffer pn
#define PRF_B(pn) do {                                                                    \
    const char* bpn_ = ldsp + (pn) * 65536 + bBase;                                       \
    bfr[0][0] = *(const short8*)(bpn_ + offk0);        bfr[0][1] = *(const short8*)(bpn_ + offk1); \
    bfr[1][0] = *(const short8*)(bpn_ + 2048 + offk0); bfr[1][1] = *(const short8*)(bpn_ + 2048 + offk1); \
    bfr[2][0] = *(const short8*)(bpn_ + 4096 + offk0); bfr[2][1] = *(const short8*)(bpn_ + 4096 + offk1); \
    bfr[3][0] = *(const short8*)(bpn_ + 6144 + offk0); bfr[3][1] = *(const short8*)(bpn_ + 6144 + offk1); \
  } while (0)

#define MMA(fc, R) do {                                                                   \
    __builtin_amdgcn_s_setprio(1);                                                        \
    _Pragma("unroll")                                                                     \
    for (int n_ = 0; n_ < 4; ++n_) {                                                      \
      acc[2 * (fc)][n_]     = __builtin_amdgcn_mfma_f32_16x16x32_bf16(R[0], bfr[n_][0], acc[2 * (fc)][n_], 0, 0, 0);     \
      acc[2 * (fc)][n_]     = __builtin_amdgcn_mfma_f32_16x16x32_bf16(R[1], bfr[n_][1], acc[2 * (fc)][n_], 0, 0, 0);     \
      acc[2 * (fc) + 1][n_] = __builtin_amdgcn_mfma_f32_16x16x32_bf16(R[2], bfr[n_][0], acc[2 * (fc) + 1][n_], 0, 0, 0); \
      acc[2 * (fc) + 1][n_] = __builtin_amdgcn_mfma_f32_16x16x32_bf16(R[3], bfr[n_][1], acc[2 * (fc) + 1][n_], 0, 0, 0); \
    }                                                                                     \
    __builtin_amdgcn_s_setprio(0);                                                        \
  } while (0)

#define SBAR do {                                                                         \
    __builtin_amdgcn_sched_barrier(0);                                                    \
    __builtin_amdgcn_s_barrier();                                                         \
    __builtin_amdgcn_sched_barrier(0);                                                    \
  } while (0)

// body: compute CUR=(fc, RC), prefetch NEXT=(pn,fn)->RN
#define BODY(fc, RC, pn, fn, RN, STG_STMT, WAIT_STMT) do {                                \
    STG_STMT;                                                                             \
    WAIT_STMT;                                                                            \
    SBAR;                                                                                 \
    PRF_A(pn, fn, RN);                                                                    \
    MMA(fc, RC);                                                                          \
  } while (0)

// buffer-boundary body: additionally reload bfr from buffer pn AFTER the MFMAs
#define BODYB(fc, RC, pn, fn, RN, STG_STMT, WAIT_STMT) do {                               \
    STG_STMT;                                                                             \
    WAIT_STMT;                                                                            \
    SBAR;                                                                                 \
    PRF_A(pn, fn, RN);                                                                    \
    MMA(fc, RC);                                                                          \
    __builtin_amdgcn_sched_barrier(0);                                                    \
    PRF_B(pn);                                                                            \
  } while (0)

__global__ __launch_bounds__(512, 2) void gemm_kernel(const unsigned short* __restrict__ A,
    const unsigned short* __restrict__ Bt, const float* __restrict__ bias,
    float* __restrict__ C) {
  __shared__ char lds[131072];
  char* ldsp = (char*)lds;
  const int tid = threadIdx.x;
  const int lane = tid & 63;
  const int wid = tid >> 6;
  const int wr = wid >> 2;            // 0..1  (M)
  const int wc = wid & 3;             // 0..3  (N)
  const int q = lane >> 4;
  const int r = lane & 15;
  const int bid = blockIdx.x;
  const int nt_ = bid & 3;            // XCD-affine: bid%8 fixes (n-panel, k-half)
  const int kh = (bid >> 2) & 1;
  const int mt = bid >> 3;            // 0..31
  const int gm0 = mt * 256;
  const int gn0 = nt_ * 256;
  const unsigned kbyte0 = (unsigned)kh * KHALF * 2;

  const char* gA = (const char*)A;
  const char* gB = (const char*)Bt;

  // staging constants: srow = tid>>3 (0..63); chunk pre-swizzled by row&7
  const int srow = tid >> 3;
  const int scol = ((tid & 7) ^ (srow & 7)) << 4;
  const unsigned baseAlo = (unsigned)(gm0 + srow) * ROWB + kbyte0 + scol;
  const unsigned baseAhi = baseAlo + 128u * ROWB;
  const unsigned baseB0  = (unsigned)(gn0 + srow) * ROWB + kbyte0 + scol;
  const unsigned baseB1  = (unsigned)(gn0 + 64 + srow) * ROWB + kbyte0 + scol;
  const int dA = tid * 16;

  // read-side constants (swizzled chunk offsets; offk1 = offk0 ^ 64)
  const int s7 = r & 7;
  const int offk0 = ((q ^ s7) << 4);
  const int offk1 = (((q + 4) ^ s7) << 4);
  const int aBase = wr * 16384 + r * 128;
  const int bBase = 32768 + (wc >> 1) * 16384 + ((wc & 1) * 64 + r) * 128;

  float4v acc[8][4];
#pragma unroll
  for (int m = 0; m < 8; m++)
#pragma unroll
    for (int n = 0; n < 4; n++) acc[m][n] = (float4v){0.f, 0.f, 0.f, 0.f};
  short8 bfr[4][2];
  short8 aRA[4], aRB[4];

  // prologue: buf0 (t0) fully + buf1.B (t1); wait until buf0 resident; prime regs
  STG_A(0, 0, 0); STG_A(0, 1, 0); STG_B(0, 0, 0); STG_B(0, 1, 0);
  STG_B(1, 0, 1); STG_B(1, 1, 1);
  VMW(4);
  SBAR;
  PRF_A(0, 0, aRA);
  PRF_B(0);

  // steady state: VMW(4) at bodies 4/8; ledger (r3, re-checked with prefetch):
  //  body4 VMW completes {B(1)prev, A(1)fg0, A(1)fg1} -> PRF_A(1,0)+PRF_B(1) legal
  //  body8 VMW completes {B(0,t2), A(0,t2)}           -> PRF_A(0,0)+PRF_B(0) legal
#pragma unroll 1
  for (int i = 0; i < NITER - 1; ++i) {
    const int t1 = 2 * i + 1, t2 = 2 * i + 2, t3 = 2 * i + 3;
    BODY (0, aRA, 0, 1, aRB, STG_A(1, 0, t1), ;);
    BODY (1, aRB, 0, 2, aRA, STG_A(1, 1, t1), ;);
    BODY (2, aRA, 0, 3, aRB, STG_B(0, 0, t2), ;);
    BODYB(3, aRB, 1, 0, aRA, STG_B(0, 1, t2), VMW(4));
    BODY (0, aRA, 1, 1, aRB, STG_A(0, 0, t2), ;);
    BODY (1, aRB, 1, 2, aRA, STG_A(0, 1, t2), ;);
    BODY (2, aRA, 1, 3, aRB, STG_B(1, 0, t3), ;);
    BODYB(3, aRB, 0, 0, aRA, STG_B(1, 1, t3), VMW(4));
  }
  // final iteration: stage only buf1.A(NT-1); drain at body 4; no prefetch past end
  BODY (0, aRA, 0, 1, aRB, STG_A(1, 0, NT - 1), ;);
  BODY (1, aRB, 0, 2, aRA, STG_A(1, 1, NT - 1), ;);
  BODY (2, aRA, 0, 3, aRB, ;, ;);
  BODYB(3, aRB, 1, 0, aRA, ;, VMW(0));
  BODY (0, aRA, 1, 1, aRB, ;, ;);
  BODY (1, aRB, 1, 2, aRA, ;, ;);
  BODY (2, aRA, 1, 3, aRB, ;, ;);
  SBAR;
  MMA(3, aRB);

  // epilogue: kh==0 blocks fold in the T0 bias (exactly once per C element)
  float bv[4] = {0.f, 0.f, 0.f, 0.f};
  if (kh == 0) {
    const float* bp = bias + gn0 + wc * 64 + r;
#pragma unroll
    for (int n = 0; n < 4; n++) bv[n] = bp[n * 16];
  }
  float* Cb = C + (size_t)(gm0 + wr * 128) * NDIM + (gn0 + wc * 64);
#pragma unroll
  for (int m = 0; m < 8; m++)
#pragma unroll
    for (int n = 0; n < 4; n++)
#pragma unroll
      for (int v = 0; v < 4; v++)
        atomicAdd(&Cb[(size_t)(m * 16 + q * 4 + v) * NDIM + (n * 16 + r)], acc[m][n][v] + bv[n]);
}

extern "C" void kernel_launch(void* const* d_in, const int* in_sizes, int n_in,
                              void* d_out, int out_size, void* d_ws, size_t ws_size,
                              hipStream_t stream) {
  const float* x    = (const float*)d_in[0];   // [8192,1024]
  const float* mean = (const float*)d_in[1];   // [1024,1024,11]
  const float* lv   = (const float*)d_in[2];   // [1024,1024,11]
  const float* W    = (const float*)d_in[3];   // [1024,1024]
  const float* eps  = (const float*)d_in[4];   // [1,1024,1024,11]
  float* out = (float*)d_out;                  // [8192*1024] + [1] kl

  // ws layout: A bf16 (184.5 MB) | Bt bf16 (23.1 MB) | bias (4 KB)
  unsigned short* Abf = (unsigned short*)d_ws;
  unsigned short* Bt  = (unsigned short*)((char*)d_ws + (size_t)MDIM * ROWB);
  float* bias = (float*)((char*)d_ws + (size_t)MDIM * ROWB + (size_t)NDIM * ROWB);
  float* kl = out + (size_t)MDIM * NDIM;

  hipMemsetAsync(out, 0, ((size_t)MDIM * NDIM + 1) * sizeof(float), stream);
  hipMemsetAsync(bias, 0, NDIM * sizeof(float), stream);
  prep_A_kernel<<<MDIM, 256, 0, stream>>>(x, (unsigned int*)Abf);
  prep_B_kernel<<<1024, 256, 0, stream>>>((const float4*)mean, (const float4*)lv, W,
                                          (const float4*)eps, Bt, kl, bias);
  gemm_kernel<<<256, 512, 0, stream>>>(Abf, Bt, bias, out);
}

// Round 5
// 381.201 us; speedup vs baseline: 1.1006x; 1.1006x over previous
//
#include <hip/hip_runtime.h>

#define MDIM 8192
#define NDIM 1024
#define FIN  1024
#define DP1  11
#define KDIM 11264            // FIN * 11  (t, T2..T10, x) -- T0 folded into bias
#define KHALF 5632            // split-K half (k elements)
#define ROWB 22528            // bytes per K-row of A / Bt (KDIM * 2)
#define HOFS 2883584u         // 128 rows * ROWB
#define FGOFS 1441792u        // 64 rows * ROWB
#define NT 88                 // K-tiles (of 64) per half
#define NITER 44              // NT / 2

typedef __attribute__((ext_vector_type(8))) short short8;
typedef __attribute__((ext_vector_type(4))) float float4v;
typedef const __attribute__((address_space(1))) unsigned int* gptr_t;
typedef __attribute__((address_space(3))) unsigned int* lptr_t;

// pack two fp32 -> bf16x2 (RNE): low16 = bf16(a), high16 = bf16(b)
__device__ __forceinline__ unsigned int pk2(float a, float b) {
  unsigned int ua = __float_as_uint(a), ub = __float_as_uint(b);
  ua += 0x7FFFu + ((ua >> 16) & 1u);
  ub += 0x7FFFu + ((ub >> 16) & 1u);
  return __builtin_amdgcn_perm(ub, ua, 0x07060302);
}

__device__ __forceinline__ unsigned short bf16rne(float a) {
  unsigned int u = __float_as_uint(a);
  u += 0x7FFFu + ((u >> 16) & 1u);
  return (unsigned short)(u >> 16);
}

__device__ __forceinline__ float fast_tanh(float x) {
  float e = __expf(2.f * x);
  return 1.f - 2.f / (e + 1.f);
}

struct Cheb { float t, T2, T3, T4, T5, T6, T7, T8, T9, T10; };
__device__ __forceinline__ Cheb cheb_eval(float x) {
  Cheb c;
  c.t = fast_tanh(x);
  const float t2 = 2.f * c.t;
  c.T2 = t2 * c.t - 1.f;
  c.T3 = t2 * c.T2 - c.t;
  c.T4 = t2 * c.T3 - c.T2;
  c.T5 = t2 * c.T4 - c.T3;
  c.T6 = t2 * c.T5 - c.T4;
  c.T7 = t2 * c.T6 - c.T5;
  c.T8 = t2 * c.T7 - c.T6;
  c.T9 = t2 * c.T8 - c.T7;
  c.T10 = t2 * c.T9 - c.T8;
  return c;
}

// 2 features (22 bf16 = 11 words), feature slots: [t, T2..T10, x]
__device__ __forceinline__ void pack_pair(float xa, float xb, unsigned int* w) {
  Cheb a = cheb_eval(xa), b = cheb_eval(xb);
  w[0] = pk2(a.t, a.T2);  w[1] = pk2(a.T3, a.T4); w[2] = pk2(a.T5, a.T6);
  w[3] = pk2(a.T7, a.T8); w[4] = pk2(a.T9, a.T10); w[5] = pk2(xa, b.t);
  w[6] = pk2(b.T2, b.T3); w[7] = pk2(b.T4, b.T5);  w[8] = pk2(b.T6, b.T7);
  w[9] = pk2(b.T8, b.T9); w[10] = pk2(b.T10, xb);
}

// ---- fused prep: bid<1024 -> prep_B (g=bid>>3, po=bid&7); else prep_A row bid-1024.
// B-blocks first so the bias/Bt long poles start immediately; A-blocks fill behind.
__global__ __launch_bounds__(256) void prep_kernel(const float* __restrict__ x,
    unsigned int* __restrict__ A, const float4* __restrict__ mean4,
    const float4* __restrict__ lv4, const float* __restrict__ W,
    const float4* __restrict__ eps4, unsigned short* __restrict__ Bt,
    float* __restrict__ kl_out, float* __restrict__ bias) {
  __shared__ __align__(16) char smem[33824];
  const int tid = threadIdx.x;
  if (blockIdx.x >= 1024) {
    // ---- prep_A: x row -> A bf16 [row][11264]; LDS-staged coalesced stores
    unsigned int* rowbuf = (unsigned int*)smem;     // 22528 B
    const int row = blockIdx.x - 1024;
    float4 xv = ((const float4*)(x + (size_t)row * FIN))[tid];
    unsigned int w[22];
    pack_pair(xv.x, xv.y, w);
    pack_pair(xv.z, xv.w, w + 11);
#pragma unroll
    for (int j = 0; j < 22; j++) rowbuf[tid * 22 + j] = w[j];
    __syncthreads();
    uint2* dst = (uint2*)((char*)A + (size_t)row * ROWB);
    const uint2* src = (const uint2*)rowbuf;
#pragma unroll
    for (int j = 0; j < 11; j++) dst[tid + j * 256] = src[tid + j * 256];
    return;
  }
  // ---- prep_B: feature-group g of 8, o-panel po of 128.
  float* cf = (float*)smem;                         // 2816 f32 = 11264 B
  unsigned int* pkb = (unsigned int*)(smem + 11264);// 5632 u32 = 22528 B
  float* wsum = (float*)(smem + 33792);
  const int g = blockIdx.x >> 3;
  const int po = blockIdx.x & 7;
  float klp = 0.f;
  float biasAcc = 0.f;
#pragma unroll 1
  for (int pr = 0; pr < 4; ++pr) {
#pragma unroll
    for (int f = 0; f < 2; ++f) {
      const int i = g * 8 + pr * 2 + f;
      const size_t b4 = (size_t)i * 2816 + po * 352;   // float4 base of [i][po*128..][*]
#pragma unroll
      for (int qq = 0; qq < 2; ++qq) {
        const int idx = qq * 256 + tid;
        if (idx < 352) {
          float4 m = mean4[b4 + idx];
          float4 l = lv4[b4 + idx];
          float4 e = eps4[b4 + idx];
          float s0 = __expf(0.5f * l.x), s1 = __expf(0.5f * l.y);
          float s2 = __expf(0.5f * l.z), s3 = __expf(0.5f * l.w);
          float4 c;
          c.x = fmaf(e.x, s0, m.x); c.y = fmaf(e.y, s1, m.y);
          c.z = fmaf(e.z, s2, m.z); c.w = fmaf(e.w, s3, m.w);
          klp += (s0 * s0 + m.x * m.x - 1.f - l.x) + (s1 * s1 + m.y * m.y - 1.f - l.y)
               + (s2 * s2 + m.z * m.z - 1.f - l.z) + (s3 * s3 + m.w * m.w - 1.f - l.w);
          ((float4*)cf)[f * 352 + idx] = c;
        }
      }
    }
    __syncthreads();                      // cf complete
    if (tid < 128) {
      const int o = tid;
      const float* ca = &cf[o * DP1];
      const float* cb = &cf[1408 + o * DP1];
      const float wa = W[(size_t)(g * 8 + pr * 2) * NDIM + po * 128 + o];
      const float wb = W[(size_t)(g * 8 + pr * 2 + 1) * NDIM + po * 128 + o];
      biasAcc += ca[0] + cb[0];
      unsigned int* dq = &pkb[o * 44 + pr * 11];
      dq[0] = pk2(ca[1], ca[2]); dq[1] = pk2(ca[3], ca[4]); dq[2] = pk2(ca[5], ca[6]);
      dq[3] = pk2(ca[7], ca[8]); dq[4] = pk2(ca[9], ca[10]); dq[5] = pk2(wa, cb[1]);
      dq[6] = pk2(cb[2], cb[3]); dq[7] = pk2(cb[4], cb[5]); dq[8] = pk2(cb[6], cb[7]);
      dq[9] = pk2(cb[8], cb[9]); dq[10] = pk2(cb[10], wb);
    }
    __syncthreads();                      // pkb slice done; cf reusable
  }
  // write 128 o-rows x 176 B (11 uint4 each)
#pragma unroll
  for (int it = 0; it < 6; ++it) {
    const int cc = it * 256 + tid;
    if (cc < 1408) {
      const int o = cc / 11, c = cc - o * 11;
      uint4 v = *(const uint4*)&pkb[o * 44 + c * 4];
      *(uint4*)((char*)Bt + (size_t)(po * 128 + o) * ROWB + g * 176 + c * 16) = v;
    }
  }
  if (tid < 128) atomicAdd(&bias[po * 128 + tid], biasAcc);
#pragma unroll
  for (int off = 32; off > 0; off >>= 1) klp += __shfl_down(klp, off, 64);
  if ((tid & 63) == 0) wsum[tid >> 6] = klp;
  __syncthreads();
  if (tid == 0) atomicAdd(kl_out, 0.5f * (wsum[0] + wsum[1] + wsum[2] + wsum[3]));
}

// ---- GEMM: 256x256 tile, BK=64, 8 waves (2M x 4N, 128x64 each), split-K x2.
// r3 schedule (one barrier per phase, reads-before-barrier, VMW(4) at bodies 4/8).
// Reads/MFMAs grouped by k-half so the cluster can start after the k0 operands.
// Epilogue: kh=1 plain f32 stores to out; kh=0 bf16 partial to C0 (no atomics).
#define VMW(N) asm volatile("s_waitcnt vmcnt(" #N ")" ::: "memory")

// A f-group fg: LDS rows {fg*64..+63} u {128+fg*64..+63} (f-slices 2fg,2fg+1 of both wr)
#define STG_A(p, fg, t) do {                                                              \
    __builtin_amdgcn_global_load_lds((gptr_t)(gA + baseAlo + (fg) * FGOFS + (unsigned)(t) * 128u), \
        (lptr_t)(ldsp + (p) * 65536 + (fg) * 8192 + dA), 16, 0, 0);                       \
    __builtin_amdgcn_global_load_lds((gptr_t)(gA + baseAhi + (fg) * FGOFS + (unsigned)(t) * 128u), \
        (lptr_t)(ldsp + (p) * 65536 + 16384 + (fg) * 8192 + dA), 16, 0, 0);               \
  } while (0)

#define STG_B(p, h, t) do {                                                               \
    __builtin_amdgcn_global_load_lds((gptr_t)(gB + baseB0 + (h) * HOFS + (unsigned)(t) * 128u), \
        (lptr_t)(ldsp + (p) * 65536 + 32768 + (h) * 16384 + dA), 16, 0, 0);               \
    __builtin_amdgcn_global_load_lds((gptr_t)(gB + baseB1 + (h) * HOFS + (unsigned)(t) * 128u), \
        (lptr_t)(ldsp + (p) * 65536 + 32768 + (h) * 16384 + 8192 + dA), 16, 0, 0);        \
  } while (0)

#define PH(p, f, STG_STMT, WAIT_STMT) do {                                                \
    const char* ap_ = ldsp + (p) * 65536 + aBase + (f) * 4096;                            \
    if ((f) == 0) {                                                                       \
      const char* bp_ = ldsp + (p) * 65536 + bBase;                                       \
      bfr[0][0] = *(const short8*)(bp_ + offk0);                                          \
      bfr[1][0] = *(const short8*)(bp_ + 2048 + offk0);                                   \
      bfr[2][0] = *(const short8*)(bp_ + 4096 + offk0);                                   \
      bfr[3][0] = *(const short8*)(bp_ + 6144 + offk0);                                   \
    }                                                                                     \
    short8 a00 = *(const short8*)(ap_ + offk0);                                           \
    short8 a10 = *(const short8*)(ap_ + 2048 + offk0);                                    \
    if ((f) == 0) {                                                                       \
      const char* bp_ = ldsp + (p) * 65536 + bBase;                                       \
      bfr[0][1] = *(const short8*)(bp_ + offk1);                                          \
      bfr[1][1] = *(const short8*)(bp_ + 2048 + offk1);                                   \
      bfr[2][1] = *(const short8*)(bp_ + 4096 + offk1);                                   \
      bfr[3][1] = *(const short8*)(bp_ + 6144 + offk1);                                   \
    }                                                                                     \
    short8 a01 = *(const short8*)(ap_ + offk1);                                           \
    short8 a11 = *(const short8*)(ap_ + 2048 + offk1);                                    \
    STG_STMT;                                                                             \
    WAIT_STMT;                                                                            \
    __builtin_amdgcn_sched_barrier(0);                                                    \
    __builtin_amdgcn_s_barrier();                                                         \
    __builtin_amdgcn_sched_barrier(0);                                                    \
    __builtin_amdgcn_s_setprio(1);                                                        \
    _Pragma("unroll")                                                                     \
    for (int n_ = 0; n_ < 4; ++n_) {                                                      \
      acc[2 * (f)][n_]     = __builtin_amdgcn_mfma_f32_16x16x32_bf16(a00, bfr[n_][0], acc[2 * (f)][n_], 0, 0, 0);     \
      acc[2 * (f) + 1][n_] = __builtin_amdgcn_mfma_f32_16x16x32_bf16(a10, bfr[n_][0], acc[2 * (f) + 1][n_], 0, 0, 0); \
    }                                                                                     \
    _Pragma("unroll")                                                                     \
    for (int n_ = 0; n_ < 4; ++n_) {                                                      \
      acc[2 * (f)][n_]     = __builtin_amdgcn_mfma_f32_16x16x32_bf16(a01, bfr[n_][1], acc[2 * (f)][n_], 0, 0, 0);     \
      acc[2 * (f) + 1][n_] = __builtin_amdgcn_mfma_f32_16x16x32_bf16(a11, bfr[n_][1], acc[2 * (f) + 1][n_], 0, 0, 0); \
    }                                                                                     \
    __builtin_amdgcn_s_setprio(0);                                                        \
  } while (0)

__global__ __launch_bounds__(512, 2) void gemm_kernel(const unsigned short* __restrict__ A,
    const unsigned short* __restrict__ Bt, float* __restrict__ C,
    unsigned short* __restrict__ C0) {
  __shared__ char lds[131072];
  char* ldsp = (char*)lds;
  const int tid = threadIdx.x;
  const int lane = tid & 63;
  const int wid = tid >> 6;
  const int wr = wid >> 2;            // 0..1  (M)
  const int wc = wid & 3;             // 0..3  (N)
  const int q = lane >> 4;
  const int r = lane & 15;
  const int bid = blockIdx.x;
  const int nt_ = bid & 3;            // XCD-affine: bid%8 fixes (n-panel, k-half)
  const int kh = (bid >> 2) & 1;
  const int mt = bid >> 3;            // 0..31
  const int gm0 = mt * 256;
  const int gn0 = nt_ * 256;
  const unsigned kbyte0 = (unsigned)kh * KHALF * 2;

  const char* gA = (const char*)A;
  const char* gB = (const char*)Bt;

  // staging constants: srow = tid>>3 (0..63); chunk pre-swizzled by row&7
  const int srow = tid >> 3;
  const int scol = ((tid & 7) ^ (srow & 7)) << 4;
  const unsigned baseAlo = (unsigned)(gm0 + srow) * ROWB + kbyte0 + scol;
  const unsigned baseAhi = baseAlo + 128u * ROWB;
  const unsigned baseB0  = (unsigned)(gn0 + srow) * ROWB + kbyte0 + scol;
  const unsigned baseB1  = (unsigned)(gn0 + 64 + srow) * ROWB + kbyte0 + scol;
  const int dA = tid * 16;

  // read-side constants (swizzled chunk offsets; offk1 = offk0 ^ 64)
  const int s7 = r & 7;
  const int offk0 = ((q ^ s7) << 4);
  const int offk1 = (((q + 4) ^ s7) << 4);
  const int aBase = wr * 16384 + r * 128;
  const int bBase = 32768 + (wc >> 1) * 16384 + ((wc & 1) * 64 + r) * 128;

  float4v acc[8][4];
#pragma unroll
  for (int m = 0; m < 8; m++)
#pragma unroll
    for (int n = 0; n < 4; n++) acc[m][n] = (float4v){0.f, 0.f, 0.f, 0.f};
  short8 bfr[4][2];

  // prologue: buf0 (t0) fully + buf1.B (t1); wait until buf0 resident
  STG_A(0, 0, 0); STG_A(0, 1, 0); STG_B(0, 0, 0); STG_B(0, 1, 0);
  STG_B(1, 0, 1); STG_B(1, 1, 1);
  VMW(4);
  __builtin_amdgcn_sched_barrier(0);
  __builtin_amdgcn_s_barrier();
  __builtin_amdgcn_sched_barrier(0);

  // steady state: one barrier per phase; VMW(4) at bodies 4/8 covers all read
  // deadlines (ledger: VMW4 completes {B(1)prev, A(1)}, VMW8 completes {B(0), A(0)})
#pragma unroll 1
  for (int i = 0; i < NITER - 1; ++i) {
    const int t1 = 2 * i + 1, t2 = 2 * i + 2, t3 = 2 * i + 3;
    PH(0, 0, STG_A(1, 0, t1), ;);
    PH(0, 1, STG_A(1, 1, t1), ;);
    PH(0, 2, STG_B(0, 0, t2), ;);
    PH(0, 3, STG_B(0, 1, t2), VMW(4));
    PH(1, 0, STG_A(0, 0, t2), ;);
    PH(1, 1, STG_A(0, 1, t2), ;);
    PH(1, 2, STG_B(1, 0, t3), ;);
    PH(1, 3, STG_B(1, 1, t3), VMW(4));
  }
  // final iteration: stage only buf1.A(NT-1); drain at body 4
  PH(0, 0, STG_A(1, 0, NT - 1), ;);
  PH(0, 1, STG_A(1, 1, NT - 1), ;);
  PH(0, 2, ;, ;);
  PH(0, 3, ;, VMW(0));
  PH(1, 0, ;, ;);
  PH(1, 1, ;, ;);
  PH(1, 2, ;, ;);
  PH(1, 3, ;, ;);

  // epilogue: kh=1 -> plain f32 stores to C; kh=0 -> bf16 partial to C0.
  if (kh) {
    float* Cb = C + (size_t)(gm0 + wr * 128) * NDIM + (gn0 + wc * 64);
#pragma unroll
    for (int m = 0; m < 8; m++)
#pragma unroll
      for (int n = 0; n < 4; n++)
#pragma unroll
        for (int v = 0; v < 4; v++)
          Cb[(size_t)(m * 16 + q * 4 + v) * NDIM + (n * 16 + r)] = acc[m][n][v];
  } else {
    unsigned short* Pb = C0 + (size_t)(gm0 + wr * 128) * NDIM + (gn0 + wc * 64);
#pragma unroll
    for (int m = 0; m < 8; m++)
#pragma unroll
      for (int n = 0; n < 4; n++)
#pragma unroll
        for (int v = 0; v < 4; v++)
          Pb[(size_t)(m * 16 + q * 4 + v) * NDIM + (n * 16 + r)] = bf16rne(acc[m][n][v]);
  }
}

// ---- out += bf16(C0) + bias ; 8 floats per thread, fully coalesced
__global__ __launch_bounds__(256) void final_add_kernel(float* __restrict__ out,
    const unsigned short* __restrict__ C0, const float* __restrict__ bias) {
  const size_t base = ((size_t)blockIdx.x * 256 + threadIdx.x) * 8;
  const int col = (int)(base & 1023);
  float4 b0 = *(const float4*)(bias + col);
  float4 b1 = *(const float4*)(bias + col + 4);
  float4 o0 = *(const float4*)(out + base);
  float4 o1 = *(const float4*)(out + base + 4);
  ushort4 p0 = *(const ushort4*)(C0 + base);
  ushort4 p1 = *(const ushort4*)(C0 + base + 4);
  o0.x += __uint_as_float((unsigned)p0.x << 16) + b0.x;
  o0.y += __uint_as_float((unsigned)p0.y << 16) + b0.y;
  o0.z += __uint_as_float((unsigned)p0.z << 16) + b0.z;
  o0.w += __uint_as_float((unsigned)p0.w << 16) + b0.w;
  o1.x += __uint_as_float((unsigned)p1.x << 16) + b1.x;
  o1.y += __uint_as_float((unsigned)p1.y << 16) + b1.y;
  o1.z += __uint_as_float((unsigned)p1.z << 16) + b1.z;
  o1.w += __uint_as_float((unsigned)p1.w << 16) + b1.w;
  *(float4*)(out + base) = o0;
  *(float4*)(out + base + 4) = o1;
}

extern "C" void kernel_launch(void* const* d_in, const int* in_sizes, int n_in,
                              void* d_out, int out_size, void* d_ws, size_t ws_size,
                              hipStream_t stream) {
  const float* x    = (const float*)d_in[0];   // [8192,1024]
  const float* mean = (const float*)d_in[1];   // [1024,1024,11]
  const float* lv   = (const float*)d_in[2];   // [1024,1024,11]
  const float* W    = (const float*)d_in[3];   // [1024,1024]
  const float* eps  = (const float*)d_in[4];   // [1,1024,1024,11]
  float* out = (float*)d_out;                  // [8192*1024] + [1] kl

  // ws layout: A bf16 (184.5 MB) | Bt bf16 (23.1 MB) | bias (4 KB) | C0 bf16 (16 MB)
  unsigned short* Abf = (unsigned short*)d_ws;
  unsigned short* Bt  = (unsigned short*)((char*)d_ws + (size_t)MDIM * ROWB);
  float* bias = (float*)((char*)d_ws + (size_t)MDIM * ROWB + (size_t)NDIM * ROWB);
  unsigned short* C0 = (unsigned short*)((char*)bias + 4096);
  float* kl = out + (size_t)MDIM * NDIM;

  hipMemsetAsync(bias, 0, NDIM * sizeof(float), stream);
  hipMemsetAsync(kl, 0, sizeof(float), stream);
  prep_kernel<<<9216, 256, 0, stream>>>(x, (unsigned int*)Abf, (const float4*)mean,
                                        (const float4*)lv, W, (const float4*)eps,
                                        Bt, kl, bias);
  gemm_kernel<<<256, 512, 0, stream>>>(Abf, Bt, out, C0);
  final_add_kernel<<<4096, 256, 0, stream>>>(out, C0, bias);
}